// Round 12
// baseline (156.638 us; speedup 1.0000x reference)
//
#include <hip/hip_runtime.h>
#include <math.h>

#define BATCH 2048
#define NN 64
#define FEAT 40
#define M 10
#define ASZ (NN * NN + 64)

typedef float v2f __attribute__((ext_vector_type(2)));

#define PKFMA_SV(acc, s_src, v_src) \
    asm("v_pk_fma_f32 %0, %1, %2, %0" : "+v"(acc) : "s"(s_src), "v"(v_src))
#define PKFMA_VV(acc, a_src, b_src) \
    asm("v_pk_fma_f32 %0, %1, %2, %0" : "+v"(acc) : "v"(a_src), "v"(b_src))

__device__ __forceinline__ float rl(float v, int l) {
    return __int_as_float(__builtin_amdgcn_readlane(__float_as_int(v), l));
}
__device__ __forceinline__ int rli(int v, int l) {
    return __builtin_amdgcn_readlane(v, l);
}
__device__ __forceinline__ float wsum(float v) {
#pragma unroll
    for (int o = 32; o >= 1; o >>= 1) v += __shfl_xor(v, o, 64);
    return v;
}

// One wave per batch element; all 2048 waves co-resident -> wall == one
// wave's latency. R12: latency surgery on the factorization.
//  (a) absolute-column pivot registers: next pivot pair == peeled registers
//      (removes the 62 ds_bpermute __shfl_downs from the critical path);
//      stores write exact zeros for lane<=k so the solve needs no mask.
//  (b) inner Schur loop software-pipelined: next row-pair ds_reads issue
//      before the current pair's fma+store (hides ~100cyc LDS latency that
//      was serialized per row-touch in R9-R11).
//  (c) solve prefetches the next L-row ahead of the 11-fma step.
__global__ __launch_bounds__(64)
__attribute__((amdgpu_waves_per_eu(2, 2)))
void muygps_kernel(
    const float* __restrict__ x,      // (20000, 40)
    const float* __restrict__ ls,     // (10,)
    const float* __restrict__ epsv,   // (10,)
    const int*   __restrict__ bidx,   // (2048,)
    const int*   __restrict__ nidx,   // (2048, 64)
    const float* __restrict__ tgt,    // (2048, 64, 10)
    float* __restrict__ out,          // pred | var | sigma
    float* __restrict__ ws)           // (M, BATCH) sigma contributions
{
    __shared__ float A[ASZ];
    __shared__ float rvb[NN];         // 1/D[k]

    const int b    = blockIdx.x;
    const int lane = threadIdx.x;

    // ---- lane's neighbor row -> 20 v2f pairs ----
    const int nv = nidx[b * NN + lane];
    const float* xr0 = x + (size_t)nv * FEAT;
    v2f xc2[FEAT / 2];
#pragma unroll
    for (int q = 0; q < FEAT / 4; ++q) {
        const float4 v = *(const float4*)(xr0 + 4 * q);
        xc2[2 * q]     = v2f{v.x, v.y};
        xc2[2 * q + 1] = v2f{v.z, v.w};
    }
    v2f nl2 = {0.f, 0.f};
#pragma unroll
    for (int q = 0; q < FEAT / 2; ++q) PKFMA_VV(nl2, xc2[q], xc2[q]);
    const float nl = nl2.x + nl2.y;

    // ---- crosswise distance ----
    const v2f* xbv = (const v2f*)(x + (size_t)bidx[b] * FEAT);
    v2f gc2 = {0.f, 0.f}, nb2 = {0.f, 0.f};
#pragma unroll
    for (int q = 0; q < FEAT / 2; ++q) {
        const v2f xbq = xbv[q];
        PKFMA_VV(gc2, xbq, xc2[q]);   // identical chains -> exact cancel on dup
        PKFMA_VV(nb2, xbq, xbq);
    }
    float cd2 = ((nb2.x + nb2.y) + nl) - 2.f * (gc2.x + gc2.y);
    cd2 = (cd2 < 0.05f) ? 0.f : cd2;  // legit d2 ~ 80 in 40-D N(0,1) data
    const float cdv = sqrtf(cd2);

    unsigned done = 0;
    const unsigned all = (1u << M) - 1u;
    while (true) {
        const int   lead = __ffs(~done) - 1;     // wave-uniform
        const float lls  = ls[lead];
        const float lep  = epsv[lead];
        const float il   = -1.0f / lls;

        // ---- Gram + kernel transform, 2 rows/iter, unroll 2 (4 streams) ----
#pragma unroll 2
        for (int i = 0; i < NN; i += 2) {
            const int ri0 = rli(nv, i), ri1 = rli(nv, i + 1);
            const v2f* rp0 = (const v2f*)(x + (size_t)ri0 * FEAT);  // uniform
            const v2f* rp1 = (const v2f*)(x + (size_t)ri1 * FEAT);
            v2f g0 = {0.f, 0.f}, g1 = {0.f, 0.f};
#pragma unroll
            for (int q = 0; q < FEAT / 2; ++q) {
                const v2f r0q = rp0[q], r1q = rp1[q];
                PKFMA_SV(g0, r0q, xc2[q]);
                PKFMA_SV(g1, r1q, xc2[q]);
            }
            const float ga = g0.x + g0.y, gb = g1.x + g1.y;
            float d2a = (rl(ga, i) + nl) - 2.f * ga;     // Gram diag = |x_i|^2
            float d2b = (rl(gb, i + 1) + nl) - 2.f * gb;
            d2a = (d2a < 0.05f) ? 0.f : d2a;
            d2b = (d2b < 0.05f) ? 0.f : d2b;
            float va = __expf(sqrtf(d2a) * il);
            float vb = __expf(sqrtf(d2b) * il);
            if (lane == i)     va += lep;
            if (lane == i + 1) vb += lep;
            A[i * NN + lane]       = va;
            A[(i + 1) * NN + lane] = vb;
        }
        const float kcv = __expf(cdv * il);

        // ---- prefetch targets ----
        float z[M + 1];
        z[0] = kcv;
        {
            const float* trow = tgt + ((size_t)b * NN + lane) * M;
#pragma unroll
            for (int q = 0; q < M / 2; ++q) {
                const float2 v = *(const float2*)(trow + 2 * q);
                z[2 * q + 1] = v.x; z[2 * q + 2] = v.y;
            }
        }

        // ---- rank-2 LDL^T, absolute-column pivots, pipelined inner ----
        float pc0 = A[lane];            // row 0 (abs cols)
        float pc1 = A[NN + lane];       // row 1
        for (int p = 0; p < 31; ++p) {
            const int k = 2 * p;
            const float d0  = rl(pc0, k);
            const float r0  = __builtin_amdgcn_rcpf(d0);
            const float cv0 = pc0 * (-r0);
            pc1 = fmaf(cv0, rl(pc0, k + 1), pc1);        // rank-1 fix row k+1
            const float d1  = rl(pc1, k + 1);
            const float r1  = __builtin_amdgcn_rcpf(d1);
            const float cv1 = pc1 * (-r1);
            // L columns: word k*NN + j = L[j][k], EXACT zeros for j<=k
            A[k * NN + lane]      = (lane > k)     ? pc0 * r0 : 0.f;
            A[k * NN + NN + lane] = (lane > k + 1) ? pc1 * r1 : 0.f;
            rvb[k]     = r0;
            rvb[k + 1] = r1;
            // peel rows k+2,k+3 (become next pivots); prefetch k+4,k+5
            float t2 = A[(k + 2) * NN + lane];
            float t3 = A[(k + 3) * NN + lane];
            float u0 = 0.f, u1 = 0.f;
            if (k + 4 < NN) { u0 = A[(k + 4) * NN + lane]; u1 = A[(k + 5) * NN + lane]; }
            t2 = fmaf(cv0, rl(pc0, k + 2), t2); t2 = fmaf(cv1, rl(pc1, k + 2), t2);
            t3 = fmaf(cv0, rl(pc0, k + 3), t3); t3 = fmaf(cv1, rl(pc1, k + 3), t3);
            for (int i = k + 4; i < NN; i += 2) {
                float a0 = u0, a1 = u1;
                if (i + 2 < NN) {                         // prefetch next pair
                    u0 = A[(i + 2) * NN + lane];
                    u1 = A[(i + 3) * NN + lane];
                }
                a0 = fmaf(cv0, rl(pc0, i), a0);     a0 = fmaf(cv1, rl(pc1, i), a0);
                a1 = fmaf(cv0, rl(pc0, i + 1), a1); a1 = fmaf(cv1, rl(pc1, i + 1), a1);
                A[i * NN + lane]       = a0;
                A[(i + 1) * NN + lane] = a1;
            }
            pc0 = t2; pc1 = t3;                          // no shfl needed
        }
        {   // final step k=62
            const float d0  = rl(pc0, 62);
            const float r0  = __builtin_amdgcn_rcpf(d0);
            const float cv0 = pc0 * (-r0);
            pc1 = fmaf(cv0, rl(pc0, 63), pc1);
            const float d1  = rl(pc1, 63);
            const float r1  = __builtin_amdgcn_rcpf(d1);
            A[62 * NN + lane] = (lane > 62) ? pc0 * r0 : 0.f;
            rvb[62] = r0;
            rvb[63] = r1;                                // row 63 never read
        }

        // ---- fused forward solves (11 ILP chains), prefetched L-rows ----
        float lr = A[lane];                              // L[lane][0] row
        for (int k = 0; k < NN - 1; ++k) {
            const float lrn = A[(k + 1) * NN + lane];    // prefetch (row 63 junk ok)
            const float lv = -lr;                        // exact 0 for lane<=k
#pragma unroll
            for (int j = 0; j < M + 1; ++j) {
                const float s = rl(z[j], k);
                z[j] = fmaf(lv, s, z[j]);
            }
            lr = lrn;
        }

        // ---- quadratic forms; lane-parallel output stores ----
        const float rvv = rvb[lane];
        const float zc  = z[0];
        const float quad = wsum(zc * zc * rvv);
        unsigned mb = 0;
#pragma unroll
        for (int m = 0; m < M; ++m)
            if (!(done & (1u << m)) && ls[m] == lls && epsv[m] == lep)
                mb |= 1u << m;
        float predv = 0.f, sigv = 0.f;
#pragma unroll
        for (int m = 0; m < M; ++m) {
            if (mb & (1u << m)) {
                const float zm = z[m + 1];
                const float pm = wsum(zc * zm * rvv);
                const float sm = wsum(zm * zm * rvv);
                if (lane == m) { predv = pm; sigv = sm; }
            }
        }
        if (lane < M && ((mb >> lane) & 1u)) {
            out[b * M + lane] = predv;
            out[BATCH * M + b * M + lane] = 1.0f - quad;
            ws[lane * BATCH + b] = sigv;
        }
        done |= mb;
        if (done == all) break;
    }
}

// 1 block x 640: wave w reduces model w's 2048 contributions.
__global__ __launch_bounds__(640)
void sigma_reduce(const float* __restrict__ ws, float* __restrict__ out) {
    const int w = threadIdx.x >> 6, lane = threadIdx.x & 63;
    const float4* p = (const float4*)(ws + w * BATCH);
    float a = 0.f;
#pragma unroll
    for (int i = 0; i < BATCH / 4 / 64; ++i) {
        const float4 v = p[i * 64 + lane];
        a += (v.x + v.y) + (v.z + v.w);
    }
    a = wsum(a);
    if (lane == 0)
        out[2 * BATCH * M + w] = a * (1.0f / (float)(BATCH * NN));
}

extern "C" void kernel_launch(void* const* d_in, const int* in_sizes, int n_in,
                              void* d_out, int out_size, void* d_ws, size_t ws_size,
                              hipStream_t stream) {
    const float* x   = (const float*)d_in[0];
    const float* lsp = (const float*)d_in[1];
    const float* ep  = (const float*)d_in[2];
    const int*   bi  = (const int*)d_in[3];
    const int*   ni  = (const int*)d_in[4];
    const float* tg  = (const float*)d_in[5];
    float* out = (float*)d_out;
    float* ws  = (float*)d_ws;        // M*BATCH*4 = 80 KB

    muygps_kernel<<<BATCH, 64, 0, stream>>>(x, lsp, ep, bi, ni, tg, out, ws);
    sigma_reduce<<<1, 640, 0, stream>>>(ws, out);
}

// Round 13
// 146.987 us; speedup vs baseline: 1.0657x; 1.0657x over previous
//
#include <hip/hip_runtime.h>
#include <math.h>

#define BATCH 2048
#define NN 64
#define FEAT 40
#define M 10
// 64 real rows + 4 pad rows: unconditional prefetch reads reach row 67.
#define ASZ (68 * NN)

typedef float v2f __attribute__((ext_vector_type(2)));

#define PKFMA_SV(acc, s_src, v_src) \
    asm("v_pk_fma_f32 %0, %1, %2, %0" : "+v"(acc) : "s"(s_src), "v"(v_src))
#define PKFMA_VV(acc, a_src, b_src) \
    asm("v_pk_fma_f32 %0, %1, %2, %0" : "+v"(acc) : "v"(a_src), "v"(b_src))

__device__ __forceinline__ float rl(float v, int l) {
    return __int_as_float(__builtin_amdgcn_readlane(__float_as_int(v), l));
}
__device__ __forceinline__ int rli(int v, int l) {
    return __builtin_amdgcn_readlane(v, l);
}
__device__ __forceinline__ float wsum(float v) {
#pragma unroll
    for (int o = 32; o >= 1; o >>= 1) v += __shfl_xor(v, o, 64);
    return v;
}

// One wave per batch element. R13: solves FUSED into the factorization.
// At step k, L's column k exists in registers (cv0/cv1), so the forward-solve
// update z[j] -= L[:,k]*z_k happens inline: the separate 63-step solve loop
// AND all L stores/reads to LDS are deleted. Pivot rows are register-carried
// two steps ahead (n2/n3 capture), so the factorization's serial spine never
// touches LDS; remaining LDS is a prefetched bulk row stream.
__global__ __launch_bounds__(64)
__attribute__((amdgpu_waves_per_eu(2, 2)))
void muygps_kernel(
    const float* __restrict__ x,      // (20000, 40)
    const float* __restrict__ ls,     // (10,)
    const float* __restrict__ epsv,   // (10,)
    const int*   __restrict__ bidx,   // (2048,)
    const int*   __restrict__ nidx,   // (2048, 64)
    const float* __restrict__ tgt,    // (2048, 64, 10)
    float* __restrict__ out,          // pred | var | sigma
    float* __restrict__ ws)           // (M, BATCH) sigma contributions
{
    __shared__ float A[ASZ];
    __shared__ float rvb[NN];         // 1/D[k]

    const int b    = blockIdx.x;
    const int lane = threadIdx.x;

    // ---- lane's neighbor row -> 20 v2f pairs ----
    const int nv = nidx[b * NN + lane];
    const float* xr0 = x + (size_t)nv * FEAT;
    v2f xc2[FEAT / 2];
#pragma unroll
    for (int q = 0; q < FEAT / 4; ++q) {
        const float4 v = *(const float4*)(xr0 + 4 * q);
        xc2[2 * q]     = v2f{v.x, v.y};
        xc2[2 * q + 1] = v2f{v.z, v.w};
    }
    v2f nl2 = {0.f, 0.f};
#pragma unroll
    for (int q = 0; q < FEAT / 2; ++q) PKFMA_VV(nl2, xc2[q], xc2[q]);
    const float nl = nl2.x + nl2.y;

    // ---- crosswise distance ----
    const v2f* xbv = (const v2f*)(x + (size_t)bidx[b] * FEAT);
    v2f gc2 = {0.f, 0.f}, nb2 = {0.f, 0.f};
#pragma unroll
    for (int q = 0; q < FEAT / 2; ++q) {
        const v2f xbq = xbv[q];
        PKFMA_VV(gc2, xbq, xc2[q]);   // identical chains -> exact cancel on dup
        PKFMA_VV(nb2, xbq, xbq);
    }
    float cd2 = ((nb2.x + nb2.y) + nl) - 2.f * (gc2.x + gc2.y);
    cd2 = (cd2 < 0.05f) ? 0.f : cd2;  // legit d2 ~ 80 in 40-D N(0,1) data
    const float cdv = sqrtf(cd2);

    unsigned done = 0;
    const unsigned all = (1u << M) - 1u;
    while (true) {
        const int   lead = __ffs(~done) - 1;     // wave-uniform
        const float lls  = ls[lead];
        const float lep  = epsv[lead];
        const float il   = -1.0f / lls;

        // ---- Gram + kernel transform, 2 rows/iter, unroll 2 ----
#pragma unroll 2
        for (int i = 0; i < NN; i += 2) {
            const int ri0 = rli(nv, i), ri1 = rli(nv, i + 1);
            const v2f* rp0 = (const v2f*)(x + (size_t)ri0 * FEAT);  // uniform
            const v2f* rp1 = (const v2f*)(x + (size_t)ri1 * FEAT);
            v2f g0 = {0.f, 0.f}, g1 = {0.f, 0.f};
#pragma unroll
            for (int q = 0; q < FEAT / 2; ++q) {
                const v2f r0q = rp0[q], r1q = rp1[q];
                PKFMA_SV(g0, r0q, xc2[q]);
                PKFMA_SV(g1, r1q, xc2[q]);
            }
            const float ga = g0.x + g0.y, gb = g1.x + g1.y;
            float d2a = (rl(ga, i) + nl) - 2.f * ga;     // Gram diag = |x_i|^2
            float d2b = (rl(gb, i + 1) + nl) - 2.f * gb;
            d2a = (d2a < 0.05f) ? 0.f : d2a;
            d2b = (d2b < 0.05f) ? 0.f : d2b;
            float va = __expf(sqrtf(d2a) * il);
            float vb = __expf(sqrtf(d2b) * il);
            if (lane == i)     va += lep;
            if (lane == i + 1) vb += lep;
            A[i * NN + lane]       = va;
            A[(i + 1) * NN + lane] = vb;
        }
        const float kcv = __expf(cdv * il);

        // ---- RHS registers: z[0]=Kc, z[1..10]=targets ----
        float z[M + 1];
        z[0] = kcv;
        {
            const float* trow = tgt + ((size_t)b * NN + lane) * M;
#pragma unroll
            for (int q = 0; q < M / 2; ++q) {
                const float2 v = *(const float2*)(trow + 2 * q);
                z[2 * q + 1] = v.x; z[2 * q + 2] = v.y;
            }
        }

        // ---- fused rank-2 LDL^T + forward solves ----
        float pc0 = A[lane];              // row 0 (pivot)
        float pc1 = A[NN + lane];         // row 1
        float n2  = A[2 * NN + lane];     // row 2 (next pivots)
        float n3  = A[3 * NN + lane];     // row 3
        for (int p = 0; p < 31; ++p) {
            const int k = 2 * p;
            // prefetch rows k+4..k+7 (bulk stream; hidden under pivot chain)
            float v0 = A[(k + 4) * NN + lane];
            float v1 = A[(k + 5) * NN + lane];
            float u0 = A[(k + 6) * NN + lane];
            float u1 = A[(k + 7) * NN + lane];
            // pivot chain (register-only)
            const float d0  = rl(pc0, k);
            const float r0  = __builtin_amdgcn_rcpf(d0);
            const float cv0 = pc0 * (-r0);
            pc1 = fmaf(cv0, rl(pc0, k + 1), pc1);
            const float d1  = rl(pc1, k + 1);
            const float r1  = __builtin_amdgcn_rcpf(d1);
            const float cv1 = pc1 * (-r1);
            rvb[k]     = r0;
            rvb[k + 1] = r1;
            // fused solve updates for columns k, k+1 (masked -L columns)
            const float lv0 = (lane > k)     ? cv0 : 0.f;
            const float lv1 = (lane > k + 1) ? cv1 : 0.f;
#pragma unroll
            for (int j = 0; j < M + 1; ++j) {
                z[j] = fmaf(lv0, rl(z[j], k), z[j]);
                z[j] = fmaf(lv1, rl(z[j], k + 1), z[j]);
            }
            // peel rows k+2,k+3 (in registers since last step) -> next pivots
            const float t2 = fmaf(cv1, rl(pc1, k + 2), fmaf(cv0, rl(pc0, k + 2), n2));
            const float t3 = fmaf(cv1, rl(pc1, k + 3), fmaf(cv0, rl(pc0, k + 3), n3));
            // iter0: rows k+4,k+5 updated in regs, captured, NOT stored
            v0 = fmaf(cv0, rl(pc0, k + 4), v0); v0 = fmaf(cv1, rl(pc1, k + 4), v0);
            v1 = fmaf(cv0, rl(pc0, k + 5), v1); v1 = fmaf(cv1, rl(pc1, k + 5), v1);
            n2 = v0; n3 = v1;
            // remaining Schur rows: prefetched read/update/write stream
            for (int i = k + 6; i < NN; i += 2) {
                float a0 = u0, a1 = u1;
                u0 = A[(i + 2) * NN + lane];   // unconditional (pad rows)
                u1 = A[(i + 3) * NN + lane];
                a0 = fmaf(cv0, rl(pc0, i), a0);     a0 = fmaf(cv1, rl(pc1, i), a0);
                a1 = fmaf(cv0, rl(pc0, i + 1), a1); a1 = fmaf(cv1, rl(pc1, i + 1), a1);
                A[i * NN + lane]       = a0;
                A[(i + 1) * NN + lane] = a1;
            }
            pc0 = t2; pc1 = t3;
        }
        {   // final step k=62 (rows 62,63 in pc0,pc1)
            const float d0  = rl(pc0, 62);
            const float r0  = __builtin_amdgcn_rcpf(d0);
            const float cv0 = pc0 * (-r0);
            pc1 = fmaf(cv0, rl(pc0, 63), pc1);
            const float d1  = rl(pc1, 63);
            const float r1  = __builtin_amdgcn_rcpf(d1);
            rvb[62] = r0;
            rvb[63] = r1;
            const float lv0 = (lane > 62) ? cv0 : 0.f;   // col 63 affects nobody
#pragma unroll
            for (int j = 0; j < M + 1; ++j)
                z[j] = fmaf(lv0, rl(z[j], 62), z[j]);
        }

        // ---- quadratic forms with D^-1; lane-parallel output stores ----
        const float rvv = rvb[lane];
        const float zc  = z[0];
        const float quad = wsum(zc * zc * rvv);
        unsigned mb = 0;
#pragma unroll
        for (int m = 0; m < M; ++m)
            if (!(done & (1u << m)) && ls[m] == lls && epsv[m] == lep)
                mb |= 1u << m;
        float predv = 0.f, sigv = 0.f;
#pragma unroll
        for (int m = 0; m < M; ++m) {
            if (mb & (1u << m)) {
                const float zm = z[m + 1];
                const float pm = wsum(zc * zm * rvv);
                const float sm = wsum(zm * zm * rvv);
                if (lane == m) { predv = pm; sigv = sm; }
            }
        }
        if (lane < M && ((mb >> lane) & 1u)) {
            out[b * M + lane] = predv;
            out[BATCH * M + b * M + lane] = 1.0f - quad;
            ws[lane * BATCH + b] = sigv;
        }
        done |= mb;
        if (done == all) break;
    }
}

// 1 block x 640: wave w reduces model w's 2048 contributions.
__global__ __launch_bounds__(640)
void sigma_reduce(const float* __restrict__ ws, float* __restrict__ out) {
    const int w = threadIdx.x >> 6, lane = threadIdx.x & 63;
    const float4* p = (const float4*)(ws + w * BATCH);
    float a = 0.f;
#pragma unroll
    for (int i = 0; i < BATCH / 4 / 64; ++i) {
        const float4 v = p[i * 64 + lane];
        a += (v.x + v.y) + (v.z + v.w);
    }
    a = wsum(a);
    if (lane == 0)
        out[2 * BATCH * M + w] = a * (1.0f / (float)(BATCH * NN));
}

extern "C" void kernel_launch(void* const* d_in, const int* in_sizes, int n_in,
                              void* d_out, int out_size, void* d_ws, size_t ws_size,
                              hipStream_t stream) {
    const float* x   = (const float*)d_in[0];
    const float* lsp = (const float*)d_in[1];
    const float* ep  = (const float*)d_in[2];
    const int*   bi  = (const int*)d_in[3];
    const int*   ni  = (const int*)d_in[4];
    const float* tg  = (const float*)d_in[5];
    float* out = (float*)d_out;
    float* ws  = (float*)d_ws;        // M*BATCH*4 = 80 KB

    muygps_kernel<<<BATCH, 64, 0, stream>>>(x, lsp, ep, bi, ni, tg, out, ws);
    sigma_reduce<<<1, 640, 0, stream>>>(ws, out);
}